// Round 6
// baseline (22.084 us; speedup 1.0000x reference)
//
#include <hip/hip_runtime.h>

#define Bdim 64
#define Mdim 50
#define Ndim 10000
#define Edim 128
#define RT   2                  // 16-row subtiles per block
#define ROWS (RT * 16)          // 32 rows/block
#define NBLK 100                // 3200 / 32
#define HSTR 280                // hfull stride in shorts (560B: 16B-aligned, bank-spread 4*odd)

using s8v   = __attribute__((ext_vector_type(8))) short;
using f32x4 = __attribute__((ext_vector_type(4))) float;

__device__ __forceinline__ short f2bf(float x) {
    union { float f; unsigned u; } v; v.f = x;
    unsigned r = (v.u + 0x7fffu + ((v.u >> 16) & 1u)) >> 16;
    return (short)r;
}

__device__ __forceinline__ s8v cvt8(float4 a, float4 b) {
    s8v v;
    v[0] = f2bf(a.x); v[1] = f2bf(a.y); v[2] = f2bf(a.z); v[3] = f2bf(a.w);
    v[4] = f2bf(b.x); v[5] = f2bf(b.y); v[6] = f2bf(b.z); v[7] = f2bf(b.w);
    return v;
}
// 8 consecutive floats at 32B-aligned p -> bf16 fragment
__device__ __forceinline__ s8v ld8(const float* __restrict__ p) {
    const float4* q = (const float4*)p;
    return cvt8(q[0], q[1]);
}

// Single fused kernel. Block t owns rows t*32 .. t*32+31 of the flat [3200] agent dim.
// Wave w owns output n-tiles {2w, 2w+1} (channels 32w..32w+31).
// Fragment convention (A and B identical, permutation cancels):
//   lane l = (r16 = l&15, h = l>>4) holds row r16, k-cols kt*32 + h*8 .. +7.
// C/D layout: col = lane&15, row = (lane>>4)*4 + reg.
__global__ __launch_bounds__(256) void k_single(
    const float* __restrict__ cities, const float* __restrict__ graph,
    const float* __restrict__ astate,
    const float* __restrict__ W_dp, const float* __restrict__ b_dp,
    const float* __restrict__ W_dc, const float* __restrict__ b_dc,
    const float* __restrict__ W_nc, const float* __restrict__ b_nc,
    const float* __restrict__ W_ps, const float* __restrict__ b_ps,
    const float* __restrict__ W_g,  const float* __restrict__ b_g,
    const float* __restrict__ W_a,  const float* __restrict__ b_a,
    float* __restrict__ out)
{
    const int t = blockIdx.x;
    const int w = threadIdx.x >> 6, l = threadIdx.x & 63;
    const int r16 = l & 15, h = l >> 4;
    const int n0 = 2 * w, n1 = 2 * w + 1;
    const int o0 = n0 * 16 + r16, o1 = n1 * 16 + r16;

    __shared__ __align__(16) short hfull[ROWS][HSTR];   // cols 0..127 = gvec, 128..255 = h

    // ---- per-lane A-row state (rows indexed by r16 within each subtile) ----
    const float* gsrc[RT];      // graph row
    const float* csrc0[RT];     // city row for idx0
    const float* csrc1[RT];     // city row for idx1
    const float* asrc[RT];      // astate row
    #pragma unroll
    for (int rt = 0; rt < RT; ++rt) {
        const int R = t * ROWS + rt * 16 + r16;
        const int b = R / Mdim;
        const float* as = astate + (size_t)R * 13;
        asrc[rt] = as;
        int i0 = (int)as[0]; i0 = min(max(i0, 0), Ndim - 1);
        int i1 = (int)as[1]; i1 = min(max(i1, 0), Ndim - 1);
        gsrc[rt]  = graph  + (size_t)b * Edim;
        csrc0[rt] = cities + ((size_t)b * Ndim + i0) * Edim;
        csrc1[rt] = cities + ((size_t)b * Ndim + i1) * Edim;
    }

    const float* wg0 = W_g + (size_t)o0 * Edim,     *wg1 = W_g + (size_t)o1 * Edim;
    const float* wdp0 = W_dp + (size_t)o0 * 2*Edim, *wdp1 = W_dp + (size_t)o1 * 2*Edim;
    const float* wa0 = W_a + (size_t)o0 * 2*Edim,   *wa1 = W_a + (size_t)o1 * 2*Edim;

    // ================= GEMM_g: gvec_tile = graph_rows @ W_g^T (+ b_g) =================
    f32x4 accg[RT][2];
    #pragma unroll
    for (int rt = 0; rt < RT; ++rt) { accg[rt][0] = (f32x4)0.f; accg[rt][1] = (f32x4)0.f; }
    #pragma unroll
    for (int kt = 0; kt < 4; ++kt) {
        const int kc = kt * 32 + h * 8;
        const s8v Bg0 = ld8(wg0 + kc);
        const s8v Bg1 = ld8(wg1 + kc);
        #pragma unroll
        for (int rt = 0; rt < RT; ++rt) {
            const s8v A = ld8(gsrc[rt] + kc);
            accg[rt][0] = __builtin_amdgcn_mfma_f32_16x16x32_bf16(A, Bg0, accg[rt][0], 0, 0, 0);
            accg[rt][1] = __builtin_amdgcn_mfma_f32_16x16x32_bf16(A, Bg1, accg[rt][1], 0, 0, 0);
        }
    }
    {
        const float bg0 = b_g[o0], bg1 = b_g[o1];
        #pragma unroll
        for (int rt = 0; rt < RT; ++rt)
            #pragma unroll
            for (int r = 0; r < 4; ++r) {
                const int row = rt * 16 + h * 4 + r;
                hfull[row][o0] = f2bf(accg[rt][0][r] + bg0);
                hfull[row][o1] = f2bf(accg[rt][1][r] + bg1);
            }
    }

    // ================= GEMM1: h_tile = X @ Wc^T  (K = 288: city0|city1|feats,bias) =====
    f32x4 acc1[RT][2];
    #pragma unroll
    for (int rt = 0; rt < RT; ++rt) { acc1[rt][0] = (f32x4)0.f; acc1[rt][1] = (f32x4)0.f; }
    #pragma unroll
    for (int kt = 0; kt < 8; ++kt) {
        const int kc = kt * 32 + h * 8;
        const s8v Bc0 = ld8(wdp0 + kc);
        const s8v Bc1 = ld8(wdp1 + kc);
        #pragma unroll
        for (int rt = 0; rt < RT; ++rt) {
            const float* src = (kt < 4) ? (csrc0[rt] + kc) : (csrc1[rt] + (kc - Edim));
            const s8v A = ld8(src);
            acc1[rt][0] = __builtin_amdgcn_mfma_f32_16x16x32_bf16(A, Bc0, acc1[rt][0], 0, 0, 0);
            acc1[rt][1] = __builtin_amdgcn_mfma_f32_16x16x32_bf16(A, Bc1, acc1[rt][1], 0, 0, 0);
        }
    }
    {   // kt = 8: cols 256..287 = [dc(4) | nc(4) | ps(3) | bias=1*b | zeros]
        s8v Bf0 = (s8v)0, Bf1 = (s8v)0;
        if (h == 0) {
            Bf0 = cvt8(*(const float4*)(W_dc + o0 * 4), *(const float4*)(W_nc + o0 * 4));
            Bf1 = cvt8(*(const float4*)(W_dc + o1 * 4), *(const float4*)(W_nc + o1 * 4));
        } else if (h == 1) {
            Bf0[0] = f2bf(W_ps[o0 * 3]); Bf0[1] = f2bf(W_ps[o0 * 3 + 1]); Bf0[2] = f2bf(W_ps[o0 * 3 + 2]);
            Bf0[3] = f2bf(b_dp[o0] + b_dc[o0] + b_nc[o0] + b_ps[o0]);
            Bf1[0] = f2bf(W_ps[o1 * 3]); Bf1[1] = f2bf(W_ps[o1 * 3 + 1]); Bf1[2] = f2bf(W_ps[o1 * 3 + 2]);
            Bf1[3] = f2bf(b_dp[o1] + b_dc[o1] + b_nc[o1] + b_ps[o1]);
        }
        #pragma unroll
        for (int rt = 0; rt < RT; ++rt) {
            s8v A = (s8v)0;
            if (h == 0) {
                #pragma unroll
                for (int j = 0; j < 8; ++j) A[j] = f2bf(asrc[rt][2 + j]);      // feats 0..7
            } else if (h == 1) {
                A[0] = f2bf(asrc[rt][10]); A[1] = f2bf(asrc[rt][11]); A[2] = f2bf(asrc[rt][12]);
                A[3] = (short)0x3F80;                                           // 1.0 (bias col)
            }
            acc1[rt][0] = __builtin_amdgcn_mfma_f32_16x16x32_bf16(A, Bf0, acc1[rt][0], 0, 0, 0);
            acc1[rt][1] = __builtin_amdgcn_mfma_f32_16x16x32_bf16(A, Bf1, acc1[rt][1], 0, 0, 0);
        }
    }
    #pragma unroll
    for (int rt = 0; rt < RT; ++rt)
        #pragma unroll
        for (int r = 0; r < 4; ++r) {
            const int row = rt * 16 + h * 4 + r;
            hfull[row][Edim + o0] = f2bf(acc1[rt][0][r]);
            hfull[row][Edim + o1] = f2bf(acc1[rt][1][r]);
        }
    __syncthreads();

    // ================= GEMM2: out = [gvec | h] @ W_a^T + b_a ==========================
    f32x4 acc2[RT][2];
    #pragma unroll
    for (int rt = 0; rt < RT; ++rt) { acc2[rt][0] = (f32x4)0.f; acc2[rt][1] = (f32x4)0.f; }
    #pragma unroll
    for (int kt = 0; kt < 8; ++kt) {
        const int kc = kt * 32 + h * 8;
        const s8v Ba0 = ld8(wa0 + kc);
        const s8v Ba1 = ld8(wa1 + kc);
        #pragma unroll
        for (int rt = 0; rt < RT; ++rt) {
            const s8v A = *(const s8v*)&hfull[rt * 16 + r16][kc];
            acc2[rt][0] = __builtin_amdgcn_mfma_f32_16x16x32_bf16(A, Ba0, acc2[rt][0], 0, 0, 0);
            acc2[rt][1] = __builtin_amdgcn_mfma_f32_16x16x32_bf16(A, Ba1, acc2[rt][1], 0, 0, 0);
        }
    }
    {
        const float ba0 = b_a[o0], ba1 = b_a[o1];
        #pragma unroll
        for (int rt = 0; rt < RT; ++rt)
            #pragma unroll
            for (int r = 0; r < 4; ++r) {
                const int R2 = t * ROWS + rt * 16 + h * 4 + r;
                out[(size_t)R2 * Edim + o0] = acc2[rt][0][r] + ba0;
                out[(size_t)R2 * Edim + o1] = acc2[rt][1][r] + ba1;
            }
    }
}

extern "C" void kernel_launch(void* const* d_in, const int* in_sizes, int n_in,
                              void* d_out, int out_size, void* d_ws, size_t ws_size,
                              hipStream_t stream) {
    const float* cities = (const float*)d_in[0];
    const float* graph  = (const float*)d_in[1];
    const float* astate = (const float*)d_in[2];
    const float* W_dp = (const float*)d_in[3];
    const float* b_dp = (const float*)d_in[4];
    const float* W_dc = (const float*)d_in[5];
    const float* b_dc = (const float*)d_in[6];
    const float* W_nc = (const float*)d_in[7];
    const float* b_nc = (const float*)d_in[8];
    const float* W_ps = (const float*)d_in[9];
    const float* b_ps = (const float*)d_in[10];
    const float* W_g  = (const float*)d_in[11];
    const float* b_g  = (const float*)d_in[12];
    const float* W_a  = (const float*)d_in[13];
    const float* b_a  = (const float*)d_in[14];
    float* out = (float*)d_out;

    hipLaunchKernelGGL(k_single, dim3(NBLK), dim3(256), 0, stream,
                       cities, graph, astate,
                       W_dp, b_dp, W_dc, b_dc, W_nc, b_nc, W_ps, b_ps,
                       W_g, b_g, W_a, b_a, out);
}

// Round 7
// 18.776 us; speedup vs baseline: 1.1762x; 1.1762x over previous
//
#include <hip/hip_runtime.h>

#define Bdim 64
#define Mdim 50
#define Ndim 10000
#define Edim 128
#define NT 200                  // row tiles of 16 (3200/16)
#define KT1 9                   // GEMM1 K-tiles (288/32); col 267 = bias (X col 267 = 1.0)
#define XSTR 296                // Xl stride in shorts (16B-aligned frags, 2-way bank max)
#define HSTR 264                // hfull stride in shorts (528B; 4*r16 bank start, 2-way max)

using s8v   = __attribute__((ext_vector_type(8))) short;
using f32x4 = __attribute__((ext_vector_type(4))) float;

// ws byte offsets — pure prefragmented weights
#define WCF_OFF 0               // [8][KT1][64] s8v : 73,728 B  (W_dp|W_dc|W_nc|W_ps|bias)
#define WAF_OFF 73728           // [8][8][64]  s8v : 65,536 B  (W_a full K=256)
#define WGF_OFF 139264          // [8][4][64]  s8v : 32,768 B  (W_g K=128)

__device__ __forceinline__ short f2bf(float x) {
    union { float f; unsigned u; } v; v.f = x;
    unsigned r = (v.u + 0x7fffu + ((v.u >> 16) & 1u)) >> 16;
    return (short)r;
}
__device__ __forceinline__ s8v cvt8(float4 a, float4 b) {
    s8v v;
    v[0] = f2bf(a.x); v[1] = f2bf(a.y); v[2] = f2bf(a.z); v[3] = f2bf(a.w);
    v[4] = f2bf(b.x); v[5] = f2bf(b.y); v[6] = f2bf(b.z); v[7] = f2bf(b.w);
    return v;
}
__device__ __forceinline__ s8v ld8(const float* __restrict__ p) {
    const float4* q = (const float4*)p;
    return cvt8(q[0], q[1]);
}

// Pure reformat: 24 blocks, no compute.
// bid 0..7  : Wc frags  (n = bid)     K=288, bias folded at col 267
// bid 8..15 : Wa frags  (n = bid-8)   K=256 (full W_a row)
// bid 16..23: Wg frags  (n = bid-16)  K=128
__global__ __launch_bounds__(256) void k_prep(
    const float* __restrict__ W_dp, const float* __restrict__ b_dp,
    const float* __restrict__ W_dc, const float* __restrict__ b_dc,
    const float* __restrict__ W_nc, const float* __restrict__ b_nc,
    const float* __restrict__ W_ps, const float* __restrict__ b_ps,
    const float* __restrict__ W_g,  const float* __restrict__ W_a,
    char* __restrict__ ws)
{
    const int bid = blockIdx.x, tid = threadIdx.x;
    const int w = tid >> 6, l = tid & 63;
    const int r16 = l & 15, h = l >> 4;

    if (bid < 8) {
        s8v* Wf = (s8v*)(ws + WCF_OFF);
        const int n = bid, o = n * 16 + r16;
        for (int kt = w; kt < KT1; kt += 4) {
            s8v v;
            #pragma unroll
            for (int j = 0; j < 8; ++j) {
                const int c = kt * 32 + h * 8 + j;
                float x = 0.f;
                if (c < 256)       x = W_dp[o * 256 + c];
                else if (c < 260)  x = W_dc[o * 4 + (c - 256)];
                else if (c < 264)  x = W_nc[o * 4 + (c - 260)];
                else if (c < 267)  x = W_ps[o * 3 + (c - 264)];
                else if (c == 267) x = b_dp[o] + b_dc[o] + b_nc[o] + b_ps[o];
                v[j] = f2bf(x);
            }
            Wf[(n * KT1 + kt) * 64 + l] = v;
        }
    } else if (bid < 16) {
        s8v* Wf = (s8v*)(ws + WAF_OFF);
        const int n = bid - 8, o = n * 16 + r16;
        for (int kt = w; kt < 8; kt += 4)
            Wf[(n * 8 + kt) * 64 + l] = ld8(W_a + (size_t)o * 256 + kt * 32 + h * 8);
    } else {
        s8v* Wf = (s8v*)(ws + WGF_OFF);
        const int n = bid - 16, o = n * 16 + r16;
        const int kt = w;
        Wf[(n * 4 + kt) * 64 + l] = ld8(W_g + (size_t)o * Edim + kt * 32 + h * 8);
    }
}

// 200 blocks x 256 thr. Block t: rows 16t..16t+15. Wave w owns n-tiles {2w, 2w+1}.
// Phases: stage(Xl, Gl2) | GEMM_g -> hfull[:, :128], GEMM1 -> hfull[:, 128:] | GEMM2(K=256).
__global__ __launch_bounds__(256) void k_main(
    const float* __restrict__ cities, const float* __restrict__ graph,
    const float* __restrict__ astate,
    const float* __restrict__ b_g, const float* __restrict__ b_a,
    const char* __restrict__ ws, float* __restrict__ out)
{
    const int t = blockIdx.x, tid = threadIdx.x;
    const int w = tid >> 6, l = tid & 63;
    const int r16 = l & 15, h = l >> 4;
    const int n0 = 2 * w, n1 = 2 * w + 1;
    const int o0 = n0 * 16 + r16, o1 = n1 * 16 + r16;

    const s8v* Wcf = (const s8v*)(ws + WCF_OFF);
    const s8v* Waf = (const s8v*)(ws + WAF_OFF);
    const s8v* Wgf = (const s8v*)(ws + WGF_OFF);

    __shared__ float asrow[16][13];
    __shared__ __align__(16) short Xl[16][XSTR];     // K=288: city0|city1|feats,bias
    __shared__ __align__(16) short Gl2[2][136];      // the <=2 distinct graph rows
    __shared__ __align__(16) short hfull[16][HSTR];  // cols 0..127 gvec, 128..255 h

    const int blo = (t * 16) / Mdim;

    // ---- stage agent rows (208 consecutive floats) + graph rows (coalesced) ----
    if (tid < 16 * 13) asrow[tid / 13][tid % 13] = astate[t * 16 * 13 + tid];
    {
        const int row = tid >> 7, c = tid & 127;          // 2 rows x 128 cols
        const int bb = min(blo + row, Bdim - 1);
        Gl2[row][c] = f2bf(graph[bb * Edim + c]);
    }
    __syncthreads();

    // ---- gather 32 city rows coalesced, convert bf16 into Xl ----
    #pragma unroll
    for (int i = 0; i < 4; ++i) {
        const int f = (i * 256 + tid) * 4;     // 0..4092, step 4
        const int r = f >> 8;                  // row 0..15
        const int c = f & 255;                 // col 0..255
        const int b = (t * 16 + r) / Mdim;
        int ci = (int)asrow[r][c < 128 ? 0 : 1];
        ci = min(max(ci, 0), Ndim - 1);
        const float4 v = *(const float4*)(cities + ((size_t)b * Ndim + ci) * Edim + (c & 127));
        Xl[r][c]     = f2bf(v.x);
        Xl[r][c + 1] = f2bf(v.y);
        Xl[r][c + 2] = f2bf(v.z);
        Xl[r][c + 3] = f2bf(v.w);
    }
    {   // feats cols 256..287: 11 feats, col 267 = 1.0 (bias), rest 0. 256 thr x 2 cols.
        const int r = tid >> 4, cc0 = (tid & 15) * 2;
        #pragma unroll
        for (int d = 0; d < 2; ++d) {
            const int cc = cc0 + d;
            float x = 0.f;
            if (cc < 11)       x = asrow[r][2 + cc];
            else if (cc == 11) x = 1.0f;
            Xl[r][256 + cc] = f2bf(x);
        }
    }
    __syncthreads();

    // ---- GEMM_g: gvec_tile = graph_rows @ W_g^T + b_g -> hfull[:, 0:128] ----
    const int selr = (t * 16 + r16) / Mdim - blo;        // 0 or 1: this lane-row's graph row
    f32x4 ag0 = (f32x4)0.f, ag1 = (f32x4)0.f;
    #pragma unroll
    for (int kt = 0; kt < 4; ++kt) {
        const int kc = kt * 32 + h * 8;
        const s8v A  = *(const s8v*)&Gl2[selr][kc];
        const s8v B0 = Wgf[(n0 * 4 + kt) * 64 + l];
        const s8v B1 = Wgf[(n1 * 4 + kt) * 64 + l];
        ag0 = __builtin_amdgcn_mfma_f32_16x16x32_bf16(A, B0, ag0, 0, 0, 0);
        ag1 = __builtin_amdgcn_mfma_f32_16x16x32_bf16(A, B1, ag1, 0, 0, 0);
    }
    {
        const float bg0 = b_g[o0], bg1 = b_g[o1];
        #pragma unroll
        for (int r = 0; r < 4; ++r) {
            const int row = h * 4 + r;                   // C/D: col=lane&15, row=(lane>>4)*4+reg
            hfull[row][o0] = f2bf(ag0[r] + bg0);
            hfull[row][o1] = f2bf(ag1[r] + bg1);
        }
    }

    // ---- GEMM1: h_tile = X @ Wc^T (bias folded) -> hfull[:, 128:256] ----
    f32x4 a10 = (f32x4)0.f, a11 = (f32x4)0.f;
    #pragma unroll
    for (int kt = 0; kt < KT1; ++kt) {
        const int kc = kt * 32 + h * 8;
        const s8v A  = *(const s8v*)&Xl[r16][kc];
        const s8v B0 = Wcf[(n0 * KT1 + kt) * 64 + l];
        const s8v B1 = Wcf[(n1 * KT1 + kt) * 64 + l];
        a10 = __builtin_amdgcn_mfma_f32_16x16x32_bf16(A, B0, a10, 0, 0, 0);
        a11 = __builtin_amdgcn_mfma_f32_16x16x32_bf16(A, B1, a11, 0, 0, 0);
    }
    #pragma unroll
    for (int r = 0; r < 4; ++r) {
        const int row = h * 4 + r;
        hfull[row][Edim + o0] = f2bf(a10[r]);
        hfull[row][Edim + o1] = f2bf(a11[r]);
    }
    __syncthreads();

    // ---- GEMM2: out = [gvec | h] @ W_a^T + b_a  (K = 256) ----
    f32x4 a20 = (f32x4)0.f, a21 = (f32x4)0.f;
    #pragma unroll
    for (int kt = 0; kt < 8; ++kt) {
        const int kc = kt * 32 + h * 8;
        const s8v A  = *(const s8v*)&hfull[r16][kc];
        const s8v B0 = Waf[(n0 * 8 + kt) * 64 + l];
        const s8v B1 = Waf[(n1 * 8 + kt) * 64 + l];
        a20 = __builtin_amdgcn_mfma_f32_16x16x32_bf16(A, B0, a20, 0, 0, 0);
        a21 = __builtin_amdgcn_mfma_f32_16x16x32_bf16(A, B1, a21, 0, 0, 0);
    }
    {
        const float ba0 = b_a[o0], ba1 = b_a[o1];
        #pragma unroll
        for (int r = 0; r < 4; ++r) {
            const int R2 = t * 16 + h * 4 + r;
            out[(size_t)R2 * Edim + o0] = a20[r] + ba0;
            out[(size_t)R2 * Edim + o1] = a21[r] + ba1;
        }
    }
}

extern "C" void kernel_launch(void* const* d_in, const int* in_sizes, int n_in,
                              void* d_out, int out_size, void* d_ws, size_t ws_size,
                              hipStream_t stream) {
    const float* cities = (const float*)d_in[0];
    const float* graph  = (const float*)d_in[1];
    const float* astate = (const float*)d_in[2];
    const float* W_dp = (const float*)d_in[3];
    const float* b_dp = (const float*)d_in[4];
    const float* W_dc = (const float*)d_in[5];
    const float* b_dc = (const float*)d_in[6];
    const float* W_nc = (const float*)d_in[7];
    const float* b_nc = (const float*)d_in[8];
    const float* W_ps = (const float*)d_in[9];
    const float* b_ps = (const float*)d_in[10];
    const float* W_g  = (const float*)d_in[11];
    const float* b_g  = (const float*)d_in[12];
    const float* W_a  = (const float*)d_in[13];
    const float* b_a  = (const float*)d_in[14];
    char* ws = (char*)d_ws;
    float* out = (float*)d_out;

    hipLaunchKernelGGL(k_prep, dim3(24), dim3(256), 0, stream,
                       W_dp, b_dp, W_dc, b_dc, W_nc, b_nc, W_ps, b_ps,
                       W_g, W_a, ws);
    hipLaunchKernelGGL(k_main, dim3(NT), dim3(256), 0, stream,
                       cities, graph, astate, b_g, b_a, ws, out);
}

// Round 8
// 16.971 us; speedup vs baseline: 1.3013x; 1.1064x over previous
//
#include <hip/hip_runtime.h>
#include <hip/hip_bf16.h>

#define Mdim 50
#define Ndim 10000
#define Edim 128
#define NT 200                  // row tiles of 16 (3200/16)
#define XSTR 296                // XL stride in shorts (16B-aligned frags, spread banks)
#define HSTR 264                // HF stride in shorts

using s8v   = __attribute__((ext_vector_type(8))) short;
using f32x4 = __attribute__((ext_vector_type(4))) float;

__device__ __forceinline__ short f2bf(float x) {
    return __builtin_bit_cast(short, __float2bfloat16(x));
}
__device__ __forceinline__ s8v cvt8(float4 a, float4 b) {
    s8v v;
    v[0] = f2bf(a.x); v[1] = f2bf(a.y); v[2] = f2bf(a.z); v[3] = f2bf(a.w);
    v[4] = f2bf(b.x); v[5] = f2bf(b.y); v[6] = f2bf(b.z); v[7] = f2bf(b.w);
    return v;
}
__device__ __forceinline__ s8v ld8g(const float* __restrict__ p) {
    const float4* q = (const float4*)p;
    return cvt8(q[0], q[1]);
}

// Single kernel, 200 blocks x 512 threads (8 waves). Block t: rows 16t..16t+15.
// Wave w owns output n-tile w (channels 16w..16w+15); its 21 B-fragments are
// register-resident, loaded in one early batch (weights are L2-resident).
// Fragment convention: lane l=(r16=l&15, h=l>>4) holds row r16, k-cols kt*32+h*8..+7.
// C/D layout: col = lane&15, row = (lane>>4)*4 + reg.
// out = [gvec | h] @ W_a^T + b_a  (K=256), gvec = graph_row @ W_g^T + b_g,
// h = X @ Wc^T (K=288, bias folded at col 267, X col 267 = 1.0).
__global__ __launch_bounds__(512) void k_one(
    const float* __restrict__ cities, const float* __restrict__ graph,
    const float* __restrict__ astate,
    const float* __restrict__ W_dp, const float* __restrict__ b_dp,
    const float* __restrict__ W_dc, const float* __restrict__ b_dc,
    const float* __restrict__ W_nc, const float* __restrict__ b_nc,
    const float* __restrict__ W_ps, const float* __restrict__ b_ps,
    const float* __restrict__ W_g,  const float* __restrict__ b_g,
    const float* __restrict__ W_a,  const float* __restrict__ b_a,
    float* __restrict__ out)
{
    const int t = blockIdx.x, tid = threadIdx.x;
    const int w = tid >> 6, l = tid & 63;
    const int r16 = l & 15, h = l >> 4;
    const int o = w * 16 + r16;          // B-row / output channel for this lane
    const int kb = h * 8;                // k-offset within a 32-wide K-tile

    __shared__ float AS[16][13];
    __shared__ __align__(16) short GL[2][136];
    __shared__ __align__(16) short XL[16][XSTR];
    __shared__ __align__(16) short HF[16][HSTR];   // cols 0..127 gvec, 128..255 h

    // ---- issue ALL B-fragment loads early (independent, latency-overlapped) ----
    s8v Bc[9], Ba[8], Bg[4];
    {
        const float* wdp = W_dp + (size_t)o * 256;
        #pragma unroll
        for (int kt = 0; kt < 8; ++kt) Bc[kt] = ld8g(wdp + kt * 32 + kb);
        s8v bf = (s8v)0;                 // kt=8: cols 256..287 = dc(4)|nc(4)|ps(3)|bias
        if (h == 0) {
            bf = cvt8(*(const float4*)(W_dc + o * 4), *(const float4*)(W_nc + o * 4));
        } else if (h == 1) {
            bf[0] = f2bf(W_ps[o * 3]); bf[1] = f2bf(W_ps[o * 3 + 1]); bf[2] = f2bf(W_ps[o * 3 + 2]);
            bf[3] = f2bf(b_dp[o] + b_dc[o] + b_nc[o] + b_ps[o]);
        }
        Bc[8] = bf;
        const float* wa = W_a + (size_t)o * 256;
        #pragma unroll
        for (int kt = 0; kt < 8; ++kt) Ba[kt] = ld8g(wa + kt * 32 + kb);
        const float* wg = W_g + (size_t)o * Edim;
        #pragma unroll
        for (int kt = 0; kt < 4; ++kt) Bg[kt] = ld8g(wg + kt * 32 + kb);
    }
    const float bgv = b_g[o], bav = b_a[o];

    // ---- stage agent rows + graph rows ----
    const int blo = (t * 16) / Mdim;
    if (tid < 16 * 13) AS[tid / 13][tid % 13] = astate[t * 16 * 13 + tid];
    if (tid < 256) {
        const int row = tid >> 7, c = tid & 127;
        const int bb = min(blo + row, 63);
        GL[row][c] = f2bf(graph[bb * Edim + c]);
    }
    __syncthreads();

    // ---- gather 32 city rows coalesced into XL (512 thr x 2 float4) ----
    #pragma unroll
    for (int i = 0; i < 2; ++i) {
        const int f = (i * 512 + tid) * 4;     // 0..4092, step 4
        const int r = f >> 8, c = f & 255;
        const int b = (t * 16 + r) / Mdim;
        int ci = (int)AS[r][c < 128 ? 0 : 1];
        ci = min(max(ci, 0), Ndim - 1);
        const float4 v = *(const float4*)(cities + ((size_t)b * Ndim + ci) * Edim + (c & 127));
        XL[r][c]     = f2bf(v.x);
        XL[r][c + 1] = f2bf(v.y);
        XL[r][c + 2] = f2bf(v.z);
        XL[r][c + 3] = f2bf(v.w);
    }
    {   // feats cols 256..287: 512 threads = 16 rows x 32 cols, one each
        const int r = tid >> 5, cc = tid & 31;
        float x = 0.f;
        if (cc < 11)       x = AS[r][2 + cc];
        else if (cc == 11) x = 1.0f;
        XL[r][256 + cc] = f2bf(x);
    }

    // ---- GEMM_g (overlaps gather): gvec -> HF[:, 0:128] ----
    const int selr = (t * 16 + r16) / Mdim - blo;      // 0/1: lane-row's graph row
    f32x4 ag = (f32x4)0.f;
    #pragma unroll
    for (int kt = 0; kt < 4; ++kt) {
        const s8v A = *(const s8v*)&GL[selr][kt * 32 + kb];
        ag = __builtin_amdgcn_mfma_f32_16x16x32_bf16(A, Bg[kt], ag, 0, 0, 0);
    }
    #pragma unroll
    for (int r = 0; r < 4; ++r) HF[h * 4 + r][o] = f2bf(ag[r] + bgv);
    __syncthreads();

    // ---- GEMM1: h = X @ Wc^T -> HF[:, 128:256] ----
    f32x4 a1 = (f32x4)0.f;
    #pragma unroll
    for (int kt = 0; kt < 9; ++kt) {
        const s8v A = *(const s8v*)&XL[r16][kt * 32 + kb];
        a1 = __builtin_amdgcn_mfma_f32_16x16x32_bf16(A, Bc[kt], a1, 0, 0, 0);
    }
    #pragma unroll
    for (int r = 0; r < 4; ++r) HF[h * 4 + r][Edim + o] = f2bf(a1[r]);
    __syncthreads();

    // ---- GEMM2: out = [gvec|h] @ W_a^T + b_a (K=256) ----
    f32x4 a2 = (f32x4)0.f;
    #pragma unroll
    for (int kt = 0; kt < 8; ++kt) {
        const s8v A = *(const s8v*)&HF[r16][kt * 32 + kb];
        a2 = __builtin_amdgcn_mfma_f32_16x16x32_bf16(A, Ba[kt], a2, 0, 0, 0);
    }
    #pragma unroll
    for (int r = 0; r < 4; ++r) {
        const int R2 = t * 16 + h * 4 + r;
        out[(size_t)R2 * Edim + o] = a2[r] + bav;
    }
}

extern "C" void kernel_launch(void* const* d_in, const int* in_sizes, int n_in,
                              void* d_out, int out_size, void* d_ws, size_t ws_size,
                              hipStream_t stream) {
    const float* cities = (const float*)d_in[0];
    const float* graph  = (const float*)d_in[1];
    const float* astate = (const float*)d_in[2];
    const float* W_dp = (const float*)d_in[3];
    const float* b_dp = (const float*)d_in[4];
    const float* W_dc = (const float*)d_in[5];
    const float* b_dc = (const float*)d_in[6];
    const float* W_nc = (const float*)d_in[7];
    const float* b_nc = (const float*)d_in[8];
    const float* W_ps = (const float*)d_in[9];
    const float* b_ps = (const float*)d_in[10];
    const float* W_g  = (const float*)d_in[11];
    const float* b_g  = (const float*)d_in[12];
    const float* W_a  = (const float*)d_in[13];
    const float* b_a  = (const float*)d_in[14];
    float* out = (float*)d_out;

    hipLaunchKernelGGL(k_one, dim3(NT), dim3(512), 0, stream,
                       cities, graph, astate,
                       W_dp, b_dp, W_dc, b_dc, W_nc, b_nc, W_ps, b_ps,
                       W_g, b_g, W_a, b_a, out);
}